// Round 1
// baseline (5836.075 us; speedup 1.0000x reference)
//
#include <hip/hip_runtime.h>
#include <cstdint>
#include <cstddef>
#include <cmath>

// ---------------------------------------------------------------------------
// GCN: h1 = relu(Agg(x@W1)+b1); h2 = relu(Agg(h1@W2)+b2); out = logsoftmax(h2@Wf+bf)
// Agg(h)[v] = dinv[v] * ( dinv[v]*h[v] + sum_{e: dst=v} dinv[src_e]*h[src_e] )
// Strategy: hs[v] = dinv[v]*h[v]; acc init = hs (self loop); scatter-add hs[src]
// into acc[dst]; finalize with dinv[v]*acc[v] in the next kernel.
// ---------------------------------------------------------------------------

__global__ __launch_bounds__(256) void k_deg(const int* __restrict__ dst,
                                             float* __restrict__ deg, int E) {
    int e = blockIdx.x * blockDim.x + threadIdx.x;
    if (e < E) unsafeAtomicAdd(&deg[dst[e]], 1.0f);
}

__global__ __launch_bounds__(256) void k_dinv(float* __restrict__ deg, int N) {
    int v = blockIdx.x * blockDim.x + threadIdx.x;
    if (v < N) deg[v] = rsqrtf(deg[v] + 1.0f);  // +1 self loop; always > 0
}

// hs = dinv * (x @ W1); acc = hs   (x: N x 128, W1: 128 x 64)
__global__ __launch_bounds__(256) void k_xform1(const float* __restrict__ x,
        const float* __restrict__ W1, const float* __restrict__ dinv,
        float* __restrict__ hs, float* __restrict__ acc, int N) {
    __shared__ float Ws[128 * 64];      // 32 KiB
    __shared__ float xs[4][128];
    int t = threadIdx.x;
    for (int i = t; i < 128 * 64; i += 256) Ws[i] = W1[i];
    int g = t >> 6, lane = t & 63;
    int v = blockIdx.x * 4 + g;
    if (v < N) {
        xs[g][lane]      = x[(size_t)v * 128 + lane];
        xs[g][lane + 64] = x[(size_t)v * 128 + 64 + lane];
    }
    __syncthreads();
    if (v >= N) return;
    float sum = 0.f;
    #pragma unroll 8
    for (int k = 0; k < 128; ++k)
        sum = fmaf(xs[g][k], Ws[k * 64 + lane], sum);
    float h = dinv[v] * sum;
    hs[((size_t)v << 6) + lane]  = h;
    acc[((size_t)v << 6) + lane] = h;
}

// acc[dst] += hs[src], 16 threads per edge, float4 per thread
__global__ __launch_bounds__(256) void k_scatter(const int* __restrict__ src,
        const int* __restrict__ dst, const float* __restrict__ hs,
        float* __restrict__ acc, int E) {
    int t = blockIdx.x * blockDim.x + threadIdx.x;
    int e = t >> 4;
    if (e >= E) return;
    int q = (t & 15) * 4;
    int u = src[e], v = dst[e];
    const float4 m = *reinterpret_cast<const float4*>(hs + ((size_t)u << 6) + q);
    float* o = acc + ((size_t)v << 6) + q;
    unsafeAtomicAdd(o + 0, m.x);
    unsafeAtomicAdd(o + 1, m.y);
    unsafeAtomicAdd(o + 2, m.z);
    unsafeAtomicAdd(o + 3, m.w);
}

// a = relu(dinv*acc_in + b1); hs2 = dinv * (a @ W2); acc2 = hs2   (W2: 64 x 64)
// acc_in and acc2 may alias (same element read-then-written by same thread).
__global__ __launch_bounds__(256) void k_xform2(const float* __restrict__ acc_in,
        const float* __restrict__ W2, const float* __restrict__ b1,
        const float* __restrict__ dinv,
        float* __restrict__ hs2, float* __restrict__ acc2, int N) {
    __shared__ float Ws[64 * 64];       // 16 KiB
    __shared__ float as[4][64];
    int t = threadIdx.x;
    for (int i = t; i < 64 * 64; i += 256) Ws[i] = W2[i];
    int g = t >> 6, lane = t & 63;
    int v = blockIdx.x * 4 + g;
    float d = 0.f;
    if (v < N) {
        d = dinv[v];
        as[g][lane] = fmaxf(fmaf(d, acc_in[((size_t)v << 6) + lane], b1[lane]), 0.f);
    }
    __syncthreads();
    if (v >= N) return;
    float sum = 0.f;
    #pragma unroll 8
    for (int c = 0; c < 64; ++c)
        sum = fmaf(as[g][c], Ws[c * 64 + lane], sum);
    float h = d * sum;
    hs2[((size_t)v << 6) + lane]  = h;
    acc2[((size_t)v << 6) + lane] = h;
}

// a = relu(dinv*acc2 + b2); z = a @ Wf + bf; out = log_softmax(z)  (Wf: 64 x 40)
__global__ __launch_bounds__(256) void k_final(const float* __restrict__ acc2,
        const float* __restrict__ Wf, const float* __restrict__ b2,
        const float* __restrict__ bf, const float* __restrict__ dinv,
        float* __restrict__ out, int N) {
    __shared__ float Ws[64 * 40];       // 10 KiB
    int t = threadIdx.x;
    for (int i = t; i < 64 * 40; i += 256) Ws[i] = Wf[i];
    int g = t >> 6, lane = t & 63;
    int v = blockIdx.x * 4 + g;
    __syncthreads();
    if (v >= N) return;
    float a = fmaxf(fmaf(dinv[v], acc2[((size_t)v << 6) + lane], b2[lane]), 0.f);
    int j = lane < 40 ? lane : 0;
    float z = 0.f;
    for (int c = 0; c < 64; ++c) {
        float ac = __shfl(a, c, 64);
        z = fmaf(ac, Ws[c * 40 + j], z);
    }
    z += bf[j];
    float m = (lane < 40) ? z : -INFINITY;
    for (int o = 32; o; o >>= 1) m = fmaxf(m, __shfl_xor(m, o, 64));
    float s = (lane < 40) ? expf(z - m) : 0.f;
    for (int o = 32; o; o >>= 1) s += __shfl_xor(s, o, 64);
    if (lane < 40) out[(size_t)v * 40 + lane] = z - m - logf(s);
}

extern "C" void kernel_launch(void* const* d_in, const int* in_sizes, int n_in,
                              void* d_out, int out_size, void* d_ws, size_t ws_size,
                              hipStream_t stream) {
    const float* x  = (const float*)d_in[0];
    const int*   ei = (const int*)d_in[1];   // [2, E]: row 0 = src, row 1 = dst
    const float* W1 = (const float*)d_in[2];
    const float* b1 = (const float*)d_in[3];
    const float* W2 = (const float*)d_in[4];
    const float* b2 = (const float*)d_in[5];
    const float* Wf = (const float*)d_in[6];
    const float* bf = (const float*)d_in[7];
    float* out = (float*)d_out;

    const int N = in_sizes[0] / 128;
    const int E = in_sizes[1] / 2;
    const int* src = ei;
    const int* dst = ei + E;

    char* ws = (char*)d_ws;
    size_t offDeg = 0;
    size_t offB1  = ((size_t)N * 4 + 255) & ~(size_t)255;
    size_t offB2  = offB1 + (((size_t)N * 64 * 4 + 255) & ~(size_t)255);
    float* deg = (float*)(ws + offDeg);   // becomes dinv after k_dinv
    float* B1  = (float*)(ws + offB1);    // hs
    float* B2  = (float*)(ws + offB2);    // acc

    hipMemsetAsync(deg, 0, (size_t)N * 4, stream);

    int blkE  = (E + 255) / 256;
    int blkN  = (N + 255) / 256;
    int blkN4 = (N + 3) / 4;
    int blkS  = (E * 16 + 255) / 256;

    k_deg   <<<blkE,  256, 0, stream>>>(dst, deg, E);
    k_dinv  <<<blkN,  256, 0, stream>>>(deg, N);
    k_xform1<<<blkN4, 256, 0, stream>>>(x, W1, deg, B1, B2, N);
    k_scatter<<<blkS, 256, 0, stream>>>(src, dst, B1, B2, E);
    k_xform2<<<blkN4, 256, 0, stream>>>(B2, W2, b1, deg, B1, B2, N);
    k_scatter<<<blkS, 256, 0, stream>>>(src, dst, B1, B2, E);
    k_final <<<blkN4, 256, 0, stream>>>(B2, Wf, b2, bf, deg, out, N);
}

// Round 2
// 909.997 us; speedup vs baseline: 6.4133x; 6.4133x over previous
//
#include <hip/hip_runtime.h>
#include <cstdint>
#include <cstddef>
#include <cmath>

// ---------------------------------------------------------------------------
// GCN via CSR aggregation (no fp atomics):
//   hs[v] = dinv[v]*(h@W)[v]
//   acc[v] = hs[v] (self loop) + sum_{e: dst=v} hs[src_e]     (register acc)
//   next layer applies dinv[v] in its prologue.
// CSR built once per call: cnt -> exclusive scan -> bin edges by dst.
// ---------------------------------------------------------------------------

__global__ __launch_bounds__(256) void k_cnt(const int* __restrict__ dst,
                                             int* __restrict__ cnt, int E) {
    int e = blockIdx.x * blockDim.x + threadIdx.x;
    if (e < E) atomicAdd(&cnt[dst[e]], 1);
}

__global__ __launch_bounds__(256) void k_dinv(const int* __restrict__ cnt,
                                              float* __restrict__ dinv, int N) {
    int v = blockIdx.x * blockDim.x + threadIdx.x;
    if (v < N) dinv[v] = rsqrtf((float)cnt[v] + 1.0f);  // +1 self loop
}

// --- 3-kernel exclusive scan over cnt[N] -> rowptr[N] (+ cursor copy) ------
__global__ __launch_bounds__(256) void k_scan1(const int* __restrict__ cnt,
        int* __restrict__ excl, int* __restrict__ bsum, int N) {
    __shared__ int s[1024];
    int t = threadIdx.x, base = blockIdx.x * 1024;
    int v[4];
    #pragma unroll
    for (int i = 0; i < 4; ++i) {
        int idx = base + t + i * 256;
        v[i] = (idx < N) ? cnt[idx] : 0;
        s[t + i * 256] = v[i];
    }
    __syncthreads();
    for (int st = 1; st < 1024; st <<= 1) {
        int tmp[4];
        #pragma unroll
        for (int i = 0; i < 4; ++i) {
            int idx = t + i * 256;
            tmp[i] = (idx >= st) ? s[idx - st] : 0;
        }
        __syncthreads();
        #pragma unroll
        for (int i = 0; i < 4; ++i) s[t + i * 256] += tmp[i];
        __syncthreads();
    }
    #pragma unroll
    for (int i = 0; i < 4; ++i) {
        int idx = base + t + i * 256;
        if (idx < N) excl[idx] = s[t + i * 256] - v[i];
    }
    if (t == 0) bsum[blockIdx.x] = s[1023];
}

__global__ void k_scan2(int* __restrict__ bsum, int nb) {
    if (threadIdx.x == 0) {
        int run = 0;
        for (int i = 0; i < nb; ++i) { int t = bsum[i]; bsum[i] = run; run += t; }
    }
}

__global__ __launch_bounds__(256) void k_scan3(int* __restrict__ excl,
        int* __restrict__ cursor, const int* __restrict__ bsum, int N) {
    int t = threadIdx.x, base = blockIdx.x * 1024;
    int off = bsum[blockIdx.x];
    #pragma unroll
    for (int i = 0; i < 4; ++i) {
        int idx = base + t + i * 256;
        if (idx < N) { int r = excl[idx] + off; excl[idx] = r; cursor[idx] = r; }
    }
}

__global__ __launch_bounds__(256) void k_bin(const int* __restrict__ src,
        const int* __restrict__ dst, int* __restrict__ cursor,
        int* __restrict__ csrc, int E) {
    int e = blockIdx.x * blockDim.x + threadIdx.x;
    if (e < E) {
        int p = atomicAdd(&cursor[dst[e]], 1);
        csrc[p] = src[e];
    }
}

// --- one wave per node: register-accumulate gathered rows ------------------
__global__ __launch_bounds__(256) void k_agg(const int* __restrict__ rowptr,
        const int* __restrict__ cnt, const int* __restrict__ csrc,
        const float* __restrict__ hs, float* __restrict__ acc, int N) {
    int w = (blockIdx.x * 256 + threadIdx.x) >> 6;
    int lane = threadIdx.x & 63;
    if (w >= N) return;
    int rs = rowptr[w], d = cnt[w];
    float a = hs[((size_t)w << 6) + lane];      // self loop
    int e = 0;
    for (; e + 4 <= d; e += 4) {
        int u0 = csrc[rs + e + 0];
        int u1 = csrc[rs + e + 1];
        int u2 = csrc[rs + e + 2];
        int u3 = csrc[rs + e + 3];
        float f0 = hs[((size_t)u0 << 6) + lane];
        float f1 = hs[((size_t)u1 << 6) + lane];
        float f2 = hs[((size_t)u2 << 6) + lane];
        float f3 = hs[((size_t)u3 << 6) + lane];
        a += f0; a += f1; a += f2; a += f3;
    }
    for (; e < d; ++e) {
        int u = csrc[rs + e];
        a += hs[((size_t)u << 6) + lane];
    }
    acc[((size_t)w << 6) + lane] = a;
}

// hs = dinv * (x @ W1)   (x: N x 128, W1: 128 x 64)
__global__ __launch_bounds__(256) void k_xform1(const float* __restrict__ x,
        const float* __restrict__ W1, const float* __restrict__ dinv,
        float* __restrict__ hs, int N) {
    __shared__ float Ws[128 * 64];      // 32 KiB
    __shared__ float xs[4][128];
    int t = threadIdx.x;
    for (int i = t; i < 128 * 64; i += 256) Ws[i] = W1[i];
    int g = t >> 6, lane = t & 63;
    int v = blockIdx.x * 4 + g;
    if (v < N) {
        xs[g][lane]      = x[(size_t)v * 128 + lane];
        xs[g][lane + 64] = x[(size_t)v * 128 + 64 + lane];
    }
    __syncthreads();
    if (v >= N) return;
    float sum = 0.f;
    #pragma unroll 8
    for (int k = 0; k < 128; ++k)
        sum = fmaf(xs[g][k], Ws[k * 64 + lane], sum);
    hs[((size_t)v << 6) + lane] = dinv[v] * sum;
}

// a = relu(dinv*acc + b1); hs2 = dinv * (a @ W2)   (W2: 64 x 64)
__global__ __launch_bounds__(256) void k_xform2(const float* __restrict__ acc_in,
        const float* __restrict__ W2, const float* __restrict__ b1,
        const float* __restrict__ dinv, float* __restrict__ hs2, int N) {
    __shared__ float Ws[64 * 64];       // 16 KiB
    __shared__ float as[4][64];
    int t = threadIdx.x;
    for (int i = t; i < 64 * 64; i += 256) Ws[i] = W2[i];
    int g = t >> 6, lane = t & 63;
    int v = blockIdx.x * 4 + g;
    float d = 0.f;
    if (v < N) {
        d = dinv[v];
        as[g][lane] = fmaxf(fmaf(d, acc_in[((size_t)v << 6) + lane], b1[lane]), 0.f);
    }
    __syncthreads();
    if (v >= N) return;
    float sum = 0.f;
    #pragma unroll 8
    for (int c = 0; c < 64; ++c)
        sum = fmaf(as[g][c], Ws[c * 64 + lane], sum);
    hs2[((size_t)v << 6) + lane] = d * sum;
}

// a = relu(dinv*acc2 + b2); z = a @ Wf + bf; out = log_softmax(z)  (Wf: 64 x 40)
__global__ __launch_bounds__(256) void k_final(const float* __restrict__ acc2,
        const float* __restrict__ Wf, const float* __restrict__ b2,
        const float* __restrict__ bf, const float* __restrict__ dinv,
        float* __restrict__ out, int N) {
    __shared__ float Ws[64 * 40];       // 10 KiB
    int t = threadIdx.x;
    for (int i = t; i < 64 * 40; i += 256) Ws[i] = Wf[i];
    int g = t >> 6, lane = t & 63;
    int v = blockIdx.x * 4 + g;
    __syncthreads();
    if (v >= N) return;
    float a = fmaxf(fmaf(dinv[v], acc2[((size_t)v << 6) + lane], b2[lane]), 0.f);
    int j = lane < 40 ? lane : 0;
    float z = 0.f;
    for (int c = 0; c < 64; ++c) {
        float ac = __shfl(a, c, 64);
        z = fmaf(ac, Ws[c * 40 + j], z);
    }
    z += bf[j];
    float m = (lane < 40) ? z : -INFINITY;
    for (int o = 32; o; o >>= 1) m = fmaxf(m, __shfl_xor(m, o, 64));
    float s = (lane < 40) ? expf(z - m) : 0.f;
    for (int o = 32; o; o >>= 1) s += __shfl_xor(s, o, 64);
    if (lane < 40) out[(size_t)v * 40 + lane] = z - m - logf(s);
}

extern "C" void kernel_launch(void* const* d_in, const int* in_sizes, int n_in,
                              void* d_out, int out_size, void* d_ws, size_t ws_size,
                              hipStream_t stream) {
    const float* x  = (const float*)d_in[0];
    const int*   ei = (const int*)d_in[1];   // [2, E]: row 0 = src, row 1 = dst
    const float* W1 = (const float*)d_in[2];
    const float* b1 = (const float*)d_in[3];
    const float* W2 = (const float*)d_in[4];
    const float* b2 = (const float*)d_in[5];
    const float* Wf = (const float*)d_in[6];
    const float* bf = (const float*)d_in[7];
    float* out = (float*)d_out;

    const int N = in_sizes[0] / 128;
    const int E = in_sizes[1] / 2;
    const int* src = ei;
    const int* dst = ei + E;

    auto align = [](size_t s) { return (s + 255) & ~(size_t)255; };
    char* ws = (char*)d_ws;
    size_t o = 0;
    int*   cnt    = (int*)(ws + o);  o += align((size_t)N * 4);
    int*   rowptr = (int*)(ws + o);  o += align((size_t)N * 4);
    int*   cursor = (int*)(ws + o);  o += align((size_t)N * 4);
    float* dinv   = (float*)(ws + o); o += align((size_t)N * 4);
    int*   bsum   = (int*)(ws + o);  o += align((size_t)1024 * 4);
    int*   csrc   = (int*)(ws + o);  o += align((size_t)E * 4);
    float* B1     = (float*)(ws + o); o += align((size_t)N * 64 * 4);  // hs
    float* B2     = (float*)(ws + o); o += align((size_t)N * 64 * 4);  // acc

    hipMemsetAsync(cnt, 0, (size_t)N * 4, stream);

    int blkE   = (E + 255) / 256;
    int blkN   = (N + 255) / 256;
    int blkN4  = (N + 3) / 4;
    int blkSc  = (N + 1023) / 1024;

    k_cnt  <<<blkE,  256, 0, stream>>>(dst, cnt, E);
    k_dinv <<<blkN,  256, 0, stream>>>(cnt, dinv, N);
    k_scan1<<<blkSc, 256, 0, stream>>>(cnt, rowptr, bsum, N);
    k_scan2<<<1,      64, 0, stream>>>(bsum, blkSc);
    k_scan3<<<blkSc, 256, 0, stream>>>(rowptr, cursor, bsum, N);
    k_bin  <<<blkE,  256, 0, stream>>>(src, dst, cursor, csrc, E);

    k_xform1<<<blkN4, 256, 0, stream>>>(x, W1, dinv, B1, N);
    k_agg   <<<blkN4, 256, 0, stream>>>(rowptr, cnt, csrc, B1, B2, N);
    k_xform2<<<blkN4, 256, 0, stream>>>(B2, W2, b1, dinv, B1, N);
    k_agg   <<<blkN4, 256, 0, stream>>>(rowptr, cnt, csrc, B1, B2, N);
    k_final <<<blkN4, 256, 0, stream>>>(B2, Wf, b2, bf, dinv, out, N);
}

// Round 3
// 587.913 us; speedup vs baseline: 9.9268x; 1.5478x over previous
//
#include <hip/hip_runtime.h>
#include <cstdint>
#include <cstddef>
#include <cmath>

// ---------------------------------------------------------------------------
// GCN via CSR aggregation. CSR built with hierarchical binning so scattered
// writes stay L2-resident (64B-line write amplification killed):
//   k_hist  : coarse bucket (dst>>8) histogram via LDS
//   k_scanB : bucket bases
//   k_pass1 : tile->LDS reorder -> coalesced packed-edge writes into tmp
//   k_p2a   : per-bucket dstLow histogram -> cnt + dinv (coalesced)
//   scan    : cnt -> rowptr
//   k_p2b   : per-bucket LDS cursors -> csrc scatter within 32KB region
// Aggregation: acc[v] = hs[v] + sum_{e:dst=v} hs[src_e], one wave per node.
// ---------------------------------------------------------------------------

#define T1 4096   // edges per pass-1 tile

__global__ __launch_bounds__(256) void k_hist(const int* __restrict__ dst,
        int* __restrict__ bucketCnt, int E, int NB) {
    __shared__ int h[512];
    int t = threadIdx.x;
    for (int i = t; i < NB; i += 256) h[i] = 0;
    __syncthreads();
    int base = blockIdx.x * T1;
    int n = min(T1, E - base);
    for (int i = t; i < n; i += 256) atomicAdd(&h[dst[base + i] >> 8], 1);
    __syncthreads();
    for (int i = t; i < NB; i += 256) if (h[i]) atomicAdd(&bucketCnt[i], h[i]);
}

__global__ __launch_bounds__(256) void k_scanB(const int* __restrict__ bucketCnt,
        int* __restrict__ bucketBase, int* __restrict__ cursor1, int NB) {
    __shared__ int s[512], o[512];
    int t = threadIdx.x;
    o[t] = s[t] = (t < NB) ? bucketCnt[t] : 0;
    o[t + 256] = s[t + 256] = (t + 256 < NB) ? bucketCnt[t + 256] : 0;
    __syncthreads();
    for (int st = 1; st < 512; st <<= 1) {
        int v0 = (t >= st) ? s[t - st] : 0;
        int v1 = (t + 256 >= st) ? s[t + 256 - st] : 0;
        __syncthreads();
        s[t] += v0; s[t + 256] += v1;
        __syncthreads();
    }
    if (t < NB)       { int e = s[t] - o[t];             bucketBase[t] = e;       cursor1[t] = e; }
    if (t + 256 < NB) { int e = s[t + 256] - o[t + 256]; bucketBase[t + 256] = e; cursor1[t + 256] = e; }
    if (t == 0) bucketBase[NB] = s[511];
}

__global__ __launch_bounds__(256) void k_pass1(const int* __restrict__ src,
        const int* __restrict__ dst, int* __restrict__ cursor1,
        unsigned int* __restrict__ tmp, int E, int NB) {
    __shared__ unsigned int pack[T1];
    __shared__ unsigned short bkt[T1];
    __shared__ int h[512], hs_[512], gbase[512];
    int t = threadIdx.x;
    for (int i = t; i < 512; i += 256) h[i] = 0;
    __syncthreads();
    int base = blockIdx.x * T1;
    int n = min(T1, E - base);
    unsigned int pk[16];
    int bl[16];
    #pragma unroll
    for (int i = 0; i < 16; ++i) {
        int idx = i * 256 + t;
        if (idx < n) {
            int s_ = src[base + idx], d = dst[base + idx];
            int b = d >> 8;
            pk[i] = (unsigned int)s_ | ((unsigned int)(d & 255) << 17);
            int lo = atomicAdd(&h[b], 1);
            bl[i] = (b << 13) | lo;
        } else bl[i] = -1;
    }
    __syncthreads();
    // inclusive scan of h into hs_
    hs_[t] = h[t]; hs_[t + 256] = h[t + 256];
    __syncthreads();
    for (int st = 1; st < 512; st <<= 1) {
        int v0 = (t >= st) ? hs_[t - st] : 0;
        int v1 = (t + 256 >= st) ? hs_[t + 256 - st] : 0;
        __syncthreads();
        hs_[t] += v0; hs_[t + 256] += v1;
        __syncthreads();
    }
    // reserve global space per bucket
    for (int i = t; i < NB; i += 256)
        gbase[i] = h[i] ? atomicAdd(&cursor1[i], h[i]) : 0;
    __syncthreads();
    // reorder into LDS
    #pragma unroll
    for (int i = 0; i < 16; ++i) {
        if (bl[i] >= 0) {
            int b = bl[i] >> 13, lo = bl[i] & 8191;
            int slot = hs_[b] - h[b] + lo;
            pack[slot] = pk[i];
            bkt[slot]  = (unsigned short)b;
        }
    }
    __syncthreads();
    // coalesced run write-out
    for (int s_ = t; s_ < n; s_ += 256) {
        int b = bkt[s_];
        tmp[gbase[b] + (s_ - (hs_[b] - h[b]))] = pack[s_];
    }
}

// per-bucket dstLow histogram -> cnt + dinv
__global__ __launch_bounds__(256) void k_p2a(const unsigned int* __restrict__ tmp,
        const int* __restrict__ bucketBase, int* __restrict__ cnt,
        float* __restrict__ dinv, int N) {
    __shared__ int c[256];
    int t = threadIdx.x, b = blockIdx.x;
    c[t] = 0;
    __syncthreads();
    int s0 = bucketBase[b], s1 = bucketBase[b + 1];
    for (int s = s0 + t; s < s1; s += 256)
        atomicAdd(&c[(tmp[s] >> 17) & 255], 1);
    __syncthreads();
    int node = b * 256 + t;
    if (node < N) {
        cnt[node]  = c[t];
        dinv[node] = rsqrtf((float)c[t] + 1.0f);   // +1 self loop
    }
}

// --- 3-kernel exclusive scan over cnt[N] -> rowptr[N] ----------------------
__global__ __launch_bounds__(256) void k_scan1(const int* __restrict__ cnt,
        int* __restrict__ excl, int* __restrict__ bsum, int N) {
    __shared__ int s[1024];
    int t = threadIdx.x, base = blockIdx.x * 1024;
    int v[4];
    #pragma unroll
    for (int i = 0; i < 4; ++i) {
        int idx = base + t + i * 256;
        v[i] = (idx < N) ? cnt[idx] : 0;
        s[t + i * 256] = v[i];
    }
    __syncthreads();
    for (int st = 1; st < 1024; st <<= 1) {
        int tmp_[4];
        #pragma unroll
        for (int i = 0; i < 4; ++i) {
            int idx = t + i * 256;
            tmp_[i] = (idx >= st) ? s[idx - st] : 0;
        }
        __syncthreads();
        #pragma unroll
        for (int i = 0; i < 4; ++i) s[t + i * 256] += tmp_[i];
        __syncthreads();
    }
    #pragma unroll
    for (int i = 0; i < 4; ++i) {
        int idx = base + t + i * 256;
        if (idx < N) excl[idx] = s[t + i * 256] - v[i];
    }
    if (t == 0) bsum[blockIdx.x] = s[1023];
}

__global__ __launch_bounds__(128) void k_scan2(int* __restrict__ bsum, int nb) {
    __shared__ int s[128], o[128];
    int t = threadIdx.x;
    o[t] = s[t] = (t < nb) ? bsum[t] : 0;
    __syncthreads();
    for (int st = 1; st < 128; st <<= 1) {
        int v = (t >= st) ? s[t - st] : 0;
        __syncthreads();
        s[t] += v;
        __syncthreads();
    }
    if (t < nb) bsum[t] = s[t] - o[t];
}

__global__ __launch_bounds__(256) void k_scan3(int* __restrict__ excl,
        const int* __restrict__ bsum, int N) {
    int t = threadIdx.x, base = blockIdx.x * 1024;
    int off = bsum[blockIdx.x];
    #pragma unroll
    for (int i = 0; i < 4; ++i) {
        int idx = base + t + i * 256;
        if (idx < N) excl[idx] += off;
    }
}

// per-bucket fine scatter: csrc[p] = src, p within L2-resident 32KB region
__global__ __launch_bounds__(256) void k_p2b(const unsigned int* __restrict__ tmp,
        const int* __restrict__ bucketBase, const int* __restrict__ rowptr,
        int* __restrict__ csrc, int N) {
    __shared__ int cur[256];
    int t = threadIdx.x, b = blockIdx.x;
    int node = b * 256 + t;
    cur[t] = (node < N) ? rowptr[node] : 0;
    __syncthreads();
    int s0 = bucketBase[b], s1 = bucketBase[b + 1];
    for (int s = s0 + t; s < s1; s += 256) {
        unsigned int p = tmp[s];
        int q = atomicAdd(&cur[(p >> 17) & 255], 1);
        csrc[q] = (int)(p & 0x1FFFFu);
    }
}

// --- one wave per node: register-accumulate gathered rows ------------------
__global__ __launch_bounds__(256) void k_agg(const int* __restrict__ rowptr,
        const int* __restrict__ cnt, const int* __restrict__ csrc,
        const float* __restrict__ hs, float* __restrict__ acc, int N) {
    int w = (blockIdx.x * 256 + threadIdx.x) >> 6;
    int lane = threadIdx.x & 63;
    if (w >= N) return;
    int rs = rowptr[w], d = cnt[w];
    float a = hs[((size_t)w << 6) + lane];      // self loop
    int e = 0;
    for (; e + 4 <= d; e += 4) {
        int u0 = csrc[rs + e + 0];
        int u1 = csrc[rs + e + 1];
        int u2 = csrc[rs + e + 2];
        int u3 = csrc[rs + e + 3];
        float f0 = hs[((size_t)u0 << 6) + lane];
        float f1 = hs[((size_t)u1 << 6) + lane];
        float f2 = hs[((size_t)u2 << 6) + lane];
        float f3 = hs[((size_t)u3 << 6) + lane];
        a += f0; a += f1; a += f2; a += f3;
    }
    for (; e < d; ++e) {
        int u = csrc[rs + e];
        a += hs[((size_t)u << 6) + lane];
    }
    acc[((size_t)w << 6) + lane] = a;
}

// hs = dinv * (x @ W1)   (x: N x 128, W1: 128 x 64)
__global__ __launch_bounds__(256) void k_xform1(const float* __restrict__ x,
        const float* __restrict__ W1, const float* __restrict__ dinv,
        float* __restrict__ hs, int N) {
    __shared__ float Ws[128 * 64];      // 32 KiB
    __shared__ float xs[4][128];
    int t = threadIdx.x;
    for (int i = t; i < 128 * 64; i += 256) Ws[i] = W1[i];
    int g = t >> 6, lane = t & 63;
    int v = blockIdx.x * 4 + g;
    if (v < N) {
        xs[g][lane]      = x[(size_t)v * 128 + lane];
        xs[g][lane + 64] = x[(size_t)v * 128 + 64 + lane];
    }
    __syncthreads();
    if (v >= N) return;
    float sum = 0.f;
    #pragma unroll 8
    for (int k = 0; k < 128; ++k)
        sum = fmaf(xs[g][k], Ws[k * 64 + lane], sum);
    hs[((size_t)v << 6) + lane] = dinv[v] * sum;
}

// a = relu(dinv*acc + b1); hs2 = dinv * (a @ W2)   (W2: 64 x 64)
__global__ __launch_bounds__(256) void k_xform2(const float* __restrict__ acc_in,
        const float* __restrict__ W2, const float* __restrict__ b1,
        const float* __restrict__ dinv, float* __restrict__ hs2, int N) {
    __shared__ float Ws[64 * 64];       // 16 KiB
    __shared__ float as[4][64];
    int t = threadIdx.x;
    for (int i = t; i < 64 * 64; i += 256) Ws[i] = W2[i];
    int g = t >> 6, lane = t & 63;
    int v = blockIdx.x * 4 + g;
    float d = 0.f;
    if (v < N) {
        d = dinv[v];
        as[g][lane] = fmaxf(fmaf(d, acc_in[((size_t)v << 6) + lane], b1[lane]), 0.f);
    }
    __syncthreads();
    if (v >= N) return;
    float sum = 0.f;
    #pragma unroll 8
    for (int c = 0; c < 64; ++c)
        sum = fmaf(as[g][c], Ws[c * 64 + lane], sum);
    hs2[((size_t)v << 6) + lane] = d * sum;
}

// a = relu(dinv*acc2 + b2); z = a @ Wf + bf; out = log_softmax(z)  (Wf: 64 x 40)
__global__ __launch_bounds__(256) void k_final(const float* __restrict__ acc2,
        const float* __restrict__ Wf, const float* __restrict__ b2,
        const float* __restrict__ bf, const float* __restrict__ dinv,
        float* __restrict__ out, int N) {
    __shared__ float Ws[64 * 40];       // 10 KiB
    int t = threadIdx.x;
    for (int i = t; i < 64 * 40; i += 256) Ws[i] = Wf[i];
    int g = t >> 6, lane = t & 63;
    int v = blockIdx.x * 4 + g;
    __syncthreads();
    if (v >= N) return;
    float a = fmaxf(fmaf(dinv[v], acc2[((size_t)v << 6) + lane], b2[lane]), 0.f);
    int j = lane < 40 ? lane : 0;
    float z = 0.f;
    for (int c = 0; c < 64; ++c) {
        float ac = __shfl(a, c, 64);
        z = fmaf(ac, Ws[c * 40 + j], z);
    }
    z += bf[j];
    float m = (lane < 40) ? z : -INFINITY;
    for (int o = 32; o; o >>= 1) m = fmaxf(m, __shfl_xor(m, o, 64));
    float s = (lane < 40) ? expf(z - m) : 0.f;
    for (int o = 32; o; o >>= 1) s += __shfl_xor(s, o, 64);
    if (lane < 40) out[(size_t)v * 40 + lane] = z - m - logf(s);
}

extern "C" void kernel_launch(void* const* d_in, const int* in_sizes, int n_in,
                              void* d_out, int out_size, void* d_ws, size_t ws_size,
                              hipStream_t stream) {
    const float* x  = (const float*)d_in[0];
    const int*   ei = (const int*)d_in[1];   // [2, E]: row 0 = src, row 1 = dst
    const float* W1 = (const float*)d_in[2];
    const float* b1 = (const float*)d_in[3];
    const float* W2 = (const float*)d_in[4];
    const float* b2 = (const float*)d_in[5];
    const float* Wf = (const float*)d_in[6];
    const float* bf = (const float*)d_in[7];
    float* out = (float*)d_out;

    const int N = in_sizes[0] / 128;
    const int E = in_sizes[1] / 2;
    const int* src = ei;
    const int* dst = ei + E;
    const int NB = (N + 255) >> 8;           // coarse buckets (256 nodes each)

    auto align = [](size_t s) { return (s + 255) & ~(size_t)255; };
    char* ws = (char*)d_ws;
    size_t o = 0;
    int*   cnt     = (int*)(ws + o);   o += align((size_t)N * 4);
    int*   rowptr  = (int*)(ws + o);   o += align((size_t)N * 4);
    float* dinv    = (float*)(ws + o); o += align((size_t)N * 4);
    int*   bucketCnt  = (int*)(ws + o); o += align(512 * 4);
    int*   bucketBase = (int*)(ws + o); o += align(513 * 4);
    int*   cursor1    = (int*)(ws + o); o += align(512 * 4);
    int*   bsum    = (int*)(ws + o);   o += align(1024 * 4);
    int*   csrc    = (int*)(ws + o);   o += align((size_t)E * 4);
    float* B1      = (float*)(ws + o); o += align((size_t)N * 64 * 4);  // hs
    float* B2      = (float*)(ws + o); o += align((size_t)N * 64 * 4);  // acc
    unsigned int* tmp = (unsigned int*)B1;   // alias: tmp dead before B1 written

    hipMemsetAsync(bucketCnt, 0, 512 * 4, stream);

    int blkT  = (E + T1 - 1) / T1;
    int blkN4 = (N + 3) / 4;
    int blkSc = (N + 1023) / 1024;

    k_hist <<<blkT, 256, 0, stream>>>(dst, bucketCnt, E, NB);
    k_scanB<<<1,    256, 0, stream>>>(bucketCnt, bucketBase, cursor1, NB);
    k_pass1<<<blkT, 256, 0, stream>>>(src, dst, cursor1, tmp, E, NB);
    k_p2a  <<<NB,   256, 0, stream>>>(tmp, bucketBase, cnt, dinv, N);
    k_scan1<<<blkSc,256, 0, stream>>>(cnt, rowptr, bsum, N);
    k_scan2<<<1,    128, 0, stream>>>(bsum, blkSc);
    k_scan3<<<blkSc,256, 0, stream>>>(rowptr, bsum, N);
    k_p2b  <<<NB,   256, 0, stream>>>(tmp, bucketBase, rowptr, csrc, N);

    k_xform1<<<blkN4, 256, 0, stream>>>(x, W1, dinv, B1, N);
    k_agg   <<<blkN4, 256, 0, stream>>>(rowptr, cnt, csrc, B1, B2, N);
    k_xform2<<<blkN4, 256, 0, stream>>>(B2, W2, b1, dinv, B1, N);
    k_agg   <<<blkN4, 256, 0, stream>>>(rowptr, cnt, csrc, B1, B2, N);
    k_final <<<blkN4, 256, 0, stream>>>(B2, Wf, b2, bf, dinv, out, N);
}

// Round 4
// 514.647 us; speedup vs baseline: 11.3400x; 1.1424x over previous
//
#include <hip/hip_runtime.h>
#include <cstdint>
#include <cstddef>
#include <cmath>

// ---------------------------------------------------------------------------
// GCN via CSR aggregation. CSR built with hierarchical binning so scattered
// writes stay L2-resident. Dense kernels are grid-stride persistent blocks:
// weights staged in LDS once per block, activations double-buffered (one
// __syncthreads per group). Final matvec is LDS-broadcast (no shfl chain).
// ---------------------------------------------------------------------------

#define T1 4096   // edges per pass-1 tile

__global__ __launch_bounds__(256) void k_hist(const int* __restrict__ dst,
        int* __restrict__ bucketCnt, int E, int NB) {
    __shared__ int h[512];
    int t = threadIdx.x;
    for (int i = t; i < NB; i += 256) h[i] = 0;
    __syncthreads();
    int base = blockIdx.x * T1;
    int n = min(T1, E - base);
    for (int i = t; i < n; i += 256) atomicAdd(&h[dst[base + i] >> 8], 1);
    __syncthreads();
    for (int i = t; i < NB; i += 256) if (h[i]) atomicAdd(&bucketCnt[i], h[i]);
}

__global__ __launch_bounds__(256) void k_scanB(const int* __restrict__ bucketCnt,
        int* __restrict__ bucketBase, int* __restrict__ cursor1, int NB) {
    __shared__ int s[512], o[512];
    int t = threadIdx.x;
    o[t] = s[t] = (t < NB) ? bucketCnt[t] : 0;
    o[t + 256] = s[t + 256] = (t + 256 < NB) ? bucketCnt[t + 256] : 0;
    __syncthreads();
    for (int st = 1; st < 512; st <<= 1) {
        int v0 = (t >= st) ? s[t - st] : 0;
        int v1 = (t + 256 >= st) ? s[t + 256 - st] : 0;
        __syncthreads();
        s[t] += v0; s[t + 256] += v1;
        __syncthreads();
    }
    if (t < NB)       { int e = s[t] - o[t];             bucketBase[t] = e;       cursor1[t] = e; }
    if (t + 256 < NB) { int e = s[t + 256] - o[t + 256]; bucketBase[t + 256] = e; cursor1[t + 256] = e; }
    if (t == 0) bucketBase[NB] = s[511];
}

__global__ __launch_bounds__(256) void k_pass1(const int* __restrict__ src,
        const int* __restrict__ dst, int* __restrict__ cursor1,
        unsigned int* __restrict__ tmp, int E, int NB) {
    __shared__ unsigned int pack[T1];
    __shared__ unsigned short bkt[T1];
    __shared__ int h[512], hs_[512], gbase[512];
    int t = threadIdx.x;
    for (int i = t; i < 512; i += 256) h[i] = 0;
    __syncthreads();
    int base = blockIdx.x * T1;
    int n = min(T1, E - base);
    unsigned int pk[16];
    int bl[16];
    #pragma unroll
    for (int i = 0; i < 16; ++i) {
        int idx = i * 256 + t;
        if (idx < n) {
            int s_ = src[base + idx], d = dst[base + idx];
            int b = d >> 8;
            pk[i] = (unsigned int)s_ | ((unsigned int)(d & 255) << 17);
            int lo = atomicAdd(&h[b], 1);
            bl[i] = (b << 13) | lo;
        } else bl[i] = -1;
    }
    __syncthreads();
    // inclusive scan of h into hs_
    hs_[t] = h[t]; hs_[t + 256] = h[t + 256];
    __syncthreads();
    for (int st = 1; st < 512; st <<= 1) {
        int v0 = (t >= st) ? hs_[t - st] : 0;
        int v1 = (t + 256 >= st) ? hs_[t + 256 - st] : 0;
        __syncthreads();
        hs_[t] += v0; hs_[t + 256] += v1;
        __syncthreads();
    }
    // reserve global space per bucket
    for (int i = t; i < NB; i += 256)
        gbase[i] = h[i] ? atomicAdd(&cursor1[i], h[i]) : 0;
    __syncthreads();
    // reorder into LDS
    #pragma unroll
    for (int i = 0; i < 16; ++i) {
        if (bl[i] >= 0) {
            int b = bl[i] >> 13, lo = bl[i] & 8191;
            int slot = hs_[b] - h[b] + lo;
            pack[slot] = pk[i];
            bkt[slot]  = (unsigned short)b;
        }
    }
    __syncthreads();
    // coalesced run write-out
    for (int s_ = t; s_ < n; s_ += 256) {
        int b = bkt[s_];
        tmp[gbase[b] + (s_ - (hs_[b] - h[b]))] = pack[s_];
    }
}

// per-bucket dstLow histogram -> cnt + dinv
__global__ __launch_bounds__(256) void k_p2a(const unsigned int* __restrict__ tmp,
        const int* __restrict__ bucketBase, int* __restrict__ cnt,
        float* __restrict__ dinv, int N) {
    __shared__ int c[256];
    int t = threadIdx.x, b = blockIdx.x;
    c[t] = 0;
    __syncthreads();
    int s0 = bucketBase[b], s1 = bucketBase[b + 1];
    for (int s = s0 + t; s < s1; s += 256)
        atomicAdd(&c[(tmp[s] >> 17) & 255], 1);
    __syncthreads();
    int node = b * 256 + t;
    if (node < N) {
        cnt[node]  = c[t];
        dinv[node] = rsqrtf((float)c[t] + 1.0f);   // +1 self loop
    }
}

// --- 3-kernel exclusive scan over cnt[N] -> rowptr[N] ----------------------
__global__ __launch_bounds__(256) void k_scan1(const int* __restrict__ cnt,
        int* __restrict__ excl, int* __restrict__ bsum, int N) {
    __shared__ int s[1024];
    int t = threadIdx.x, base = blockIdx.x * 1024;
    int v[4];
    #pragma unroll
    for (int i = 0; i < 4; ++i) {
        int idx = base + t + i * 256;
        v[i] = (idx < N) ? cnt[idx] : 0;
        s[t + i * 256] = v[i];
    }
    __syncthreads();
    for (int st = 1; st < 1024; st <<= 1) {
        int tmp_[4];
        #pragma unroll
        for (int i = 0; i < 4; ++i) {
            int idx = t + i * 256;
            tmp_[i] = (idx >= st) ? s[idx - st] : 0;
        }
        __syncthreads();
        #pragma unroll
        for (int i = 0; i < 4; ++i) s[t + i * 256] += tmp_[i];
        __syncthreads();
    }
    #pragma unroll
    for (int i = 0; i < 4; ++i) {
        int idx = base + t + i * 256;
        if (idx < N) excl[idx] = s[t + i * 256] - v[i];
    }
    if (t == 0) bsum[blockIdx.x] = s[1023];
}

__global__ __launch_bounds__(128) void k_scan2(int* __restrict__ bsum, int nb) {
    __shared__ int s[128], o[128];
    int t = threadIdx.x;
    o[t] = s[t] = (t < nb) ? bsum[t] : 0;
    __syncthreads();
    for (int st = 1; st < 128; st <<= 1) {
        int v = (t >= st) ? s[t - st] : 0;
        __syncthreads();
        s[t] += v;
        __syncthreads();
    }
    if (t < nb) bsum[t] = s[t] - o[t];
}

__global__ __launch_bounds__(256) void k_scan3(int* __restrict__ excl,
        const int* __restrict__ bsum, int N) {
    int t = threadIdx.x, base = blockIdx.x * 1024;
    int off = bsum[blockIdx.x];
    #pragma unroll
    for (int i = 0; i < 4; ++i) {
        int idx = base + t + i * 256;
        if (idx < N) excl[idx] += off;
    }
}

// per-bucket fine scatter: csrc[p] = src, p within L2-resident region
__global__ __launch_bounds__(256) void k_p2b(const unsigned int* __restrict__ tmp,
        const int* __restrict__ bucketBase, const int* __restrict__ rowptr,
        int* __restrict__ csrc, int N) {
    __shared__ int cur[256];
    int t = threadIdx.x, b = blockIdx.x;
    int node = b * 256 + t;
    cur[t] = (node < N) ? rowptr[node] : 0;
    __syncthreads();
    int s0 = bucketBase[b], s1 = bucketBase[b + 1];
    for (int s = s0 + t; s < s1; s += 256) {
        unsigned int p = tmp[s];
        int q = atomicAdd(&cur[(p >> 17) & 255], 1);
        csrc[q] = (int)(p & 0x1FFFFu);
    }
}

// --- one wave per node: register-accumulate gathered rows ------------------
__global__ __launch_bounds__(256) void k_agg(const int* __restrict__ rowptr,
        const int* __restrict__ cnt, const int* __restrict__ csrc,
        const float* __restrict__ hs, float* __restrict__ acc, int N) {
    int w = (blockIdx.x * 256 + threadIdx.x) >> 6;
    int lane = threadIdx.x & 63;
    if (w >= N) return;
    int rs = rowptr[w], d = cnt[w];
    float a = hs[((size_t)w << 6) + lane];      // self loop
    int e = 0;
    for (; e + 4 <= d; e += 4) {
        int u0 = csrc[rs + e + 0];
        int u1 = csrc[rs + e + 1];
        int u2 = csrc[rs + e + 2];
        int u3 = csrc[rs + e + 3];
        float f0 = hs[((size_t)u0 << 6) + lane];
        float f1 = hs[((size_t)u1 << 6) + lane];
        float f2 = hs[((size_t)u2 << 6) + lane];
        float f3 = hs[((size_t)u3 << 6) + lane];
        a += f0; a += f1; a += f2; a += f3;
    }
    for (; e < d; ++e) {
        int u = csrc[rs + e];
        a += hs[((size_t)u << 6) + lane];
    }
    acc[((size_t)w << 6) + lane] = a;
}

// hs = dinv * (x @ W1)   (x: N x 128, W1: 128 x 64)  -- persistent blocks
__global__ __launch_bounds__(256) void k_xform1(const float* __restrict__ x,
        const float* __restrict__ W1, const float* __restrict__ dinv,
        float* __restrict__ hs, int N, int ngrp) {
    __shared__ float Ws[128 * 64];      // 32 KiB
    __shared__ float xs[2][4][128];     // 4 KiB, double-buffered
    int t = threadIdx.x;
    for (int i = t; i < 128 * 64; i += 256) Ws[i] = W1[i];
    int g = t >> 6, lane = t & 63;
    int buf = 0;
    for (int vb = blockIdx.x; vb < ngrp; vb += gridDim.x, buf ^= 1) {
        int v = vb * 4 + g;
        if (v < N) {
            xs[buf][g][lane]      = x[(size_t)v * 128 + lane];
            xs[buf][g][lane + 64] = x[(size_t)v * 128 + 64 + lane];
        }
        __syncthreads();
        if (v < N) {
            float sum = 0.f;
            #pragma unroll 8
            for (int k = 0; k < 128; ++k)
                sum = fmaf(xs[buf][g][k], Ws[k * 64 + lane], sum);
            hs[((size_t)v << 6) + lane] = dinv[v] * sum;
        }
    }
}

// a = relu(dinv*acc + b1); hs2 = dinv * (a @ W2)   (W2: 64 x 64) -- persistent
__global__ __launch_bounds__(256) void k_xform2(const float* __restrict__ acc_in,
        const float* __restrict__ W2, const float* __restrict__ b1,
        const float* __restrict__ dinv, float* __restrict__ hs2, int N, int ngrp) {
    __shared__ float Ws[64 * 64];       // 16 KiB
    __shared__ float as[2][4][64];      // 2 KiB, double-buffered
    int t = threadIdx.x;
    for (int i = t; i < 64 * 64; i += 256) Ws[i] = W2[i];
    int g = t >> 6, lane = t & 63;
    float b1v = b1[lane];
    int buf = 0;
    for (int vb = blockIdx.x; vb < ngrp; vb += gridDim.x, buf ^= 1) {
        int v = vb * 4 + g;
        float d = 0.f;
        if (v < N) {
            d = dinv[v];
            as[buf][g][lane] = fmaxf(fmaf(d, acc_in[((size_t)v << 6) + lane], b1v), 0.f);
        }
        __syncthreads();
        if (v < N) {
            float sum = 0.f;
            #pragma unroll 8
            for (int c = 0; c < 64; ++c)
                sum = fmaf(as[buf][g][c], Ws[c * 64 + lane], sum);
            hs2[((size_t)v << 6) + lane] = d * sum;
        }
    }
}

// a = relu(dinv*acc2 + b2); z = a @ Wf + bf; out = log_softmax(z)
// LDS-broadcast matvec (no shfl chain) -- persistent blocks
__global__ __launch_bounds__(256) void k_final(const float* __restrict__ acc2,
        const float* __restrict__ Wf, const float* __restrict__ b2,
        const float* __restrict__ bf, const float* __restrict__ dinv,
        float* __restrict__ out, int N, int ngrp) {
    __shared__ float Ws[64 * 40];       // 10 KiB
    __shared__ float as[2][4][64];      // 2 KiB, double-buffered
    int t = threadIdx.x;
    for (int i = t; i < 64 * 40; i += 256) Ws[i] = Wf[i];
    int g = t >> 6, lane = t & 63;
    float b2v = b2[lane];
    float bfv = (lane < 40) ? bf[lane] : 0.f;
    int buf = 0;
    for (int vb = blockIdx.x; vb < ngrp; vb += gridDim.x, buf ^= 1) {
        int v = vb * 4 + g;
        if (v < N)
            as[buf][g][lane] = fmaxf(fmaf(dinv[v], acc2[((size_t)v << 6) + lane], b2v), 0.f);
        __syncthreads();
        if (v < N) {
            float z = bfv;
            if (lane < 40) {
                #pragma unroll 8
                for (int c = 0; c < 64; ++c)
                    z = fmaf(as[buf][g][c], Ws[c * 40 + lane], z);
            }
            float m = (lane < 40) ? z : -INFINITY;
            for (int o = 32; o; o >>= 1) m = fmaxf(m, __shfl_xor(m, o, 64));
            float s = (lane < 40) ? expf(z - m) : 0.f;
            for (int o = 32; o; o >>= 1) s += __shfl_xor(s, o, 64);
            if (lane < 40) out[(size_t)v * 40 + lane] = z - m - logf(s);
        }
    }
}

extern "C" void kernel_launch(void* const* d_in, const int* in_sizes, int n_in,
                              void* d_out, int out_size, void* d_ws, size_t ws_size,
                              hipStream_t stream) {
    const float* x  = (const float*)d_in[0];
    const int*   ei = (const int*)d_in[1];   // [2, E]: row 0 = src, row 1 = dst
    const float* W1 = (const float*)d_in[2];
    const float* b1 = (const float*)d_in[3];
    const float* W2 = (const float*)d_in[4];
    const float* b2 = (const float*)d_in[5];
    const float* Wf = (const float*)d_in[6];
    const float* bf = (const float*)d_in[7];
    float* out = (float*)d_out;

    const int N = in_sizes[0] / 128;
    const int E = in_sizes[1] / 2;
    const int* src = ei;
    const int* dst = ei + E;
    const int NB = (N + 255) >> 8;           // coarse buckets (256 nodes each)

    auto align = [](size_t s) { return (s + 255) & ~(size_t)255; };
    char* ws = (char*)d_ws;
    size_t o = 0;
    int*   cnt     = (int*)(ws + o);   o += align((size_t)N * 4);
    int*   rowptr  = (int*)(ws + o);   o += align((size_t)N * 4);
    float* dinv    = (float*)(ws + o); o += align((size_t)N * 4);
    int*   bucketCnt  = (int*)(ws + o); o += align(512 * 4);
    int*   bucketBase = (int*)(ws + o); o += align(513 * 4);
    int*   cursor1    = (int*)(ws + o); o += align(512 * 4);
    int*   bsum    = (int*)(ws + o);   o += align(1024 * 4);
    int*   csrc    = (int*)(ws + o);   o += align((size_t)E * 4);
    float* B1      = (float*)(ws + o); o += align((size_t)N * 64 * 4);  // hs
    float* B2      = (float*)(ws + o); o += align((size_t)N * 64 * 4);  // acc
    unsigned int* tmp = (unsigned int*)B1;   // alias: tmp dead before B1 written

    hipMemsetAsync(bucketCnt, 0, 512 * 4, stream);

    int blkT  = (E + T1 - 1) / T1;
    int ngrp  = (N + 3) / 4;
    int blkN4 = (ngrp < 25000) ? ngrp : 25000; // unused placeholder guard
    (void)blkN4;
    int blkSc = (N + 1023) / 1024;
    int gX1 = (ngrp < 1024) ? ngrp : 1024;   // 32+4 KiB LDS -> 4 blocks/CU
    int gX2 = (ngrp < 2048) ? ngrp : 2048;   // 18 KiB LDS  -> 8 blocks/CU
    int gF  = (ngrp < 2048) ? ngrp : 2048;

    k_hist <<<blkT, 256, 0, stream>>>(dst, bucketCnt, E, NB);
    k_scanB<<<1,    256, 0, stream>>>(bucketCnt, bucketBase, cursor1, NB);
    k_pass1<<<blkT, 256, 0, stream>>>(src, dst, cursor1, tmp, E, NB);
    k_p2a  <<<NB,   256, 0, stream>>>(tmp, bucketBase, cnt, dinv, N);
    k_scan1<<<blkSc,256, 0, stream>>>(cnt, rowptr, bsum, N);
    k_scan2<<<1,    128, 0, stream>>>(bsum, blkSc);
    k_scan3<<<blkSc,256, 0, stream>>>(rowptr, bsum, N);
    k_p2b  <<<NB,   256, 0, stream>>>(tmp, bucketBase, rowptr, csrc, N);

    int blkAgg = (N * 64 + 255) / 256;  // one wave per node
    k_xform1<<<gX1, 256, 0, stream>>>(x, W1, dinv, B1, N, ngrp);
    k_agg   <<<blkAgg, 256, 0, stream>>>(rowptr, cnt, csrc, B1, B2, N);
    k_xform2<<<gX2, 256, 0, stream>>>(B2, W2, b1, dinv, B1, N, ngrp);
    k_agg   <<<blkAgg, 256, 0, stream>>>(rowptr, cnt, csrc, B1, B2, N);
    k_final <<<gF,  256, 0, stream>>>(B2, Wf, b2, bf, dinv, out, N, ngrp);
}